// Round 1
// baseline (225.249 us; speedup 1.0000x reference)
//
#include <hip/hip_runtime.h>

// ---------------------------------------------------------------------------
// RandomForest: 100 trees, depth 5, D=256, B=8192, C=64.
// Key facts:
//  * decision = sign(w.x + b)  (sigmoid<=0.5  <=>  z<=0)
//  * reference gathers node `idx` each level with idx=2*idx+dec  => only
//    node rows 0..15 are ever used for routing; final idx in [0,32) indexes leaves.
//  * precision: bf16-split (hi+lo, 3 MFMAs) + fp64 exact recompute when
//    |z| < TAU ensures every sign matches an exact fp32/fp64 evaluation.
// ---------------------------------------------------------------------------

typedef __bf16 bf16;
typedef __attribute__((ext_vector_type(8))) __bf16 bf16x8;
typedef __attribute__((ext_vector_type(4))) float f32x4;

#define NTREES 100
#define NB     8192
#define ND     256
#define NNODES 31
#define NUSED  16
#define NLEAF  32
#define NCLS   64
#define TREES_PER_BLK 5
#define TAU 0.02f

// ---- split fp32 -> bf16 hi/lo -------------------------------------------------
__global__ void split_x_kernel(const float* __restrict__ x,
                               bf16* __restrict__ xh, bf16* __restrict__ xl) {
    int i = blockIdx.x * 256 + threadIdx.x;   // grid sized exactly: 8192*256
    float f = x[i];
    bf16 h = (bf16)f;
    xh[i] = h;
    xl[i] = (bf16)(f - (float)h);
}

__global__ void split_w_kernel(const float* __restrict__ w,
                               bf16* __restrict__ wh, bf16* __restrict__ wl) {
    int i = blockIdx.x * 256 + threadIdx.x;   // grid sized exactly: 100*16*256
    int d = i & 255;
    int r = (i >> 8) & 15;        // node row 0..15 (only used rows)
    int t = i >> 12;              // tree
    float f = w[((size_t)t * NNODES + r) * ND + d];
    bf16 h = (bf16)f;
    wh[i] = h;
    wl[i] = (bf16)(f - (float)h);
}

// ---- main: per-tree 16-node GEMM (split bf16 MFMA) + traversal ---------------
__global__ __launch_bounds__(256, 2) void forest_mfma(
    const bf16* __restrict__ xh, const bf16* __restrict__ xl,
    const bf16* __restrict__ wh, const bf16* __restrict__ wl,
    const float* __restrict__ xf,      // original fp32 x   (for exact fixup)
    const float* __restrict__ wf,      // original fp32 node_w
    const float* __restrict__ bias,    // node_b [100][31]
    unsigned char* __restrict__ idxb)  // out: leaf index [100][8192]
{
    __shared__ bf16 ldsWh[NUSED][264];   // 256 + 8 pad (keeps b128 reads bank-balanced)
    __shared__ bf16 ldsWl[NUSED][264];
    __shared__ float sc[4][32][17];      // per-wave C scratch: 32 samples x 16 nodes (+1 pad)

    const int tid  = threadIdx.x;
    const int wave = tid >> 6;
    const int lane = tid & 63;
    const int m    = lane & 15;      // A row / B col / D col selector
    const int q    = lane >> 4;      // k-octet / D row-quad
    const int tg   = blockIdx.x;     // tree group (0..19)
    const int st   = blockIdx.y;     // sample tile (0..63)
    const int sbase = st * 128 + wave * 32;   // this wave's 32 samples

    // ---- A fragments (hi+lo, 2 M-tiles of 16 samples) live in registers,
    //      reused across all TREES_PER_BLK trees. 128 VGPRs.
    bf16x8 a0h[8], a0l[8], a1h[8], a1l[8];
#pragma unroll
    for (int k = 0; k < 8; ++k) {
        size_t o0 = (size_t)(sbase + m) * ND + k * 32 + q * 8;
        size_t o1 = (size_t)(sbase + 16 + m) * ND + k * 32 + q * 8;
        a0h[k] = *(const bf16x8*)(xh + o0);
        a0l[k] = *(const bf16x8*)(xl + o0);
        a1h[k] = *(const bf16x8*)(xh + o1);
        a1l[k] = *(const bf16x8*)(xl + o1);
    }

    for (int tt = 0; tt < TREES_PER_BLK; ++tt) {
        const int t = tg * TREES_PER_BLK + tt;

        __syncthreads();   // protect ldsW from previous iteration's readers
        // stage W_t rows 0..15 (hi+lo): 512 16B-chunks per array, 256 threads
        for (int i = tid; i < 512; i += 256) {
            int r = i >> 5, c = i & 31;
            *(uint4*)&ldsWh[r][c * 8] =
                *(const uint4*)(wh + ((size_t)t * NUSED + r) * ND + c * 8);
            *(uint4*)&ldsWl[r][c * 8] =
                *(const uint4*)(wl + ((size_t)t * NUSED + r) * ND + c * 8);
        }
        __syncthreads();

        f32x4 zz4 = {0.f, 0.f, 0.f, 0.f};
        f32x4 c0a = zz4, c0b = zz4, c0c = zz4;
        f32x4 c1a = zz4, c1b = zz4, c1c = zz4;
#pragma unroll
        for (int k = 0; k < 8; ++k) {
            bf16x8 bh = *(const bf16x8*)&ldsWh[m][k * 32 + q * 8];
            bf16x8 bl = *(const bf16x8*)&ldsWl[m][k * 32 + q * 8];
            c0a = __builtin_amdgcn_mfma_f32_16x16x32_bf16(a0h[k], bh, c0a, 0, 0, 0);
            c0b = __builtin_amdgcn_mfma_f32_16x16x32_bf16(a0l[k], bh, c0b, 0, 0, 0);
            c0c = __builtin_amdgcn_mfma_f32_16x16x32_bf16(a0h[k], bl, c0c, 0, 0, 0);
            c1a = __builtin_amdgcn_mfma_f32_16x16x32_bf16(a1h[k], bh, c1a, 0, 0, 0);
            c1b = __builtin_amdgcn_mfma_f32_16x16x32_bf16(a1l[k], bh, c1b, 0, 0, 0);
            c1c = __builtin_amdgcn_mfma_f32_16x16x32_bf16(a1h[k], bl, c1c, 0, 0, 0);
        }
        c0a += c0b; c0a += c0c;
        c1a += c1b; c1a += c1c;

        // C/D layout: col = lane&15 (node), row = (lane>>4)*4 + reg (sample)
#pragma unroll
        for (int r = 0; r < 4; ++r) {
            sc[wave][q * 4 + r][m]      = c0a[r];
            sc[wave][16 + q * 4 + r][m] = c1a[r];
        }
        __syncthreads();

        if (lane < 32) {
            int s = lane;
            int gs = sbase + s;
            int node = 0;
            for (int dstep = 0; dstep < 5; ++dstep) {
                float z = sc[wave][s][node] + bias[t * NNODES + node];
                bool dec;
                if (__builtin_expect(fabsf(z) < TAU, 0)) {
                    // exact recompute: fp32*fp32 products are exact in double
                    double zd = (double)bias[t * NNODES + node];
                    const float* xr = xf + (size_t)gs * ND;
                    const float* wr = wf + ((size_t)t * NNODES + node) * ND;
#pragma unroll 8
                    for (int d = 0; d < ND; ++d)
                        zd += (double)xr[d] * (double)wr[d];
                    dec = (zd <= 0.0);
                } else {
                    dec = (z <= 0.0f);
                }
                node = 2 * node + (dec ? 1 : 0);
            }
            idxb[(size_t)t * NB + gs] = (unsigned char)node;
        }
    }
}

// ---- leaf gather + forest mean ----------------------------------------------
__global__ void leaf_gather(const unsigned char* __restrict__ idxb,
                            const float* __restrict__ leaves,
                            float* __restrict__ out) {
    int tid = threadIdx.x;
    int b = blockIdx.x * 4 + (tid >> 6);   // 4 samples per block
    int c = tid & 63;
    float acc = 0.f;
#pragma unroll 4
    for (int t = 0; t < NTREES; ++t) {
        int li = idxb[(size_t)t * NB + b];          // wave-uniform load
        acc += leaves[((size_t)t * NLEAF + li) * NCLS + c];
    }
    out[(size_t)b * NCLS + c] = acc * 0.01f;
}

// ---------------------------------------------------------------------------
extern "C" void kernel_launch(void* const* d_in, const int* in_sizes, int n_in,
                              void* d_out, int out_size, void* d_ws, size_t ws_size,
                              hipStream_t stream) {
    const float* x  = (const float*)d_in[0];   // [8192,256]
    const float* nw = (const float*)d_in[1];   // [100,31,256]
    const float* nb = (const float*)d_in[2];   // [100,31]
    const float* lv = (const float*)d_in[3];   // [100,32,64]
    float* out = (float*)d_out;

    char* ws = (char*)d_ws;
    // workspace layout (16B aligned), total ~10.85 MB
    bf16* xh = (bf16*)(ws + 0);                     // 4,194,304 B
    bf16* xl = (bf16*)(ws + 4194304);               // 4,194,304 B
    bf16* wh = (bf16*)(ws + 8388608);               //   819,200 B
    bf16* wl = (bf16*)(ws + 9207808);               //   819,200 B
    unsigned char* idxb = (unsigned char*)(ws + 10027008); // 819,200 B
    if (ws_size < (size_t)10846208) return;  // fail loudly via validation

    split_x_kernel<<<NB * ND / 256, 256, 0, stream>>>(x, xh, xl);
    split_w_kernel<<<NTREES * NUSED * ND / 256, 256, 0, stream>>>(nw, wh, wl);
    forest_mfma<<<dim3(NTREES / TREES_PER_BLK, NB / 128), 256, 0, stream>>>(
        xh, xl, wh, wl, x, nw, nb, idxb);
    leaf_gather<<<NB / 4, 256, 0, stream>>>(idxb, lv, out);
}

// Round 2
// 120.986 us; speedup vs baseline: 1.8618x; 1.8618x over previous
//
#include <hip/hip_runtime.h>

// ---------------------------------------------------------------------------
// RandomForest: 100 trees, depth 5, D=256, B=8192, C=64.
//  * decision = sign(w.x + b); only node rows 0..15 route (gather-before-update).
//  * One fused GEMM: Z[8192 x 1600] = X . W^T (+bias), split-bf16 3-MFMA,
//    traversal in epilogue; near-tie decisions (|z|<TAU) queued for an exact
//    fp64 re-traversal kernel (idempotent root re-traverse).
// ---------------------------------------------------------------------------

typedef __bf16 bf16;
typedef __attribute__((ext_vector_type(8))) __bf16 bf16x8;
typedef __attribute__((ext_vector_type(4))) float f32x4;

#define NTREES 100
#define NB     8192
#define ND     256
#define NNODES 31
#define NUSED  16
#define NLEAF  32
#define NCLS   64
#define TAU    2.0e-3f
#define QCAP   8192

// ---- K1: split fp32 X -> bf16 hi/lo, A-operand-swizzled layout --------------
// layout: elem index = g*4096 + dq*128 + m*8 + e  ==  X[g*16+m][dq*8+e]
// (g = s>>4 sample-group, m = s&15, dq = d>>3). A wave's MFMA A-frag load is
// then one contiguous 1 KB segment (lane*16B).
__global__ void split_x_swz(const float* __restrict__ x,
                            bf16* __restrict__ xh, bf16* __restrict__ xl) {
    int i = blockIdx.x * 256 + threadIdx.x;       // 0 .. 262143
    int m  = i & 15;
    int dq = (i >> 4) & 31;
    int g  = i >> 9;
    const float* src = x + (size_t)(g * 16 + m) * ND + dq * 8;
    bf16 h8[8], l8[8];
#pragma unroll
    for (int e = 0; e < 8; ++e) {
        float f = src[e];
        bf16 h = (bf16)f;
        h8[e] = h;
        l8[e] = (bf16)(f - (float)h);
    }
    *(uint4*)(xh + (size_t)i * 8) = *(uint4*)h8;
    *(uint4*)(xl + (size_t)i * 8) = *(uint4*)l8;
}

// ---- K2: split fp32 W rows 0..15 -> bf16 hi/lo [100][16][256] ---------------
__global__ void split_w_kernel(const float* __restrict__ w,
                               bf16* __restrict__ wh, bf16* __restrict__ wl) {
    int i = blockIdx.x * 256 + threadIdx.x;   // 100*16*256 threads
    int d = i & 255;
    int r = (i >> 8) & 15;
    int t = i >> 12;
    float f = w[((size_t)t * NNODES + r) * ND + d];
    bf16 h = (bf16)f;
    wh[i] = h;
    wl[i] = (bf16)(f - (float)h);
}

// ---- K3: fused GEMM + traversal ---------------------------------------------
// block: 128 samples x 4 trees (64 node-cols). 4 waves, each M=32, N=64.
__global__ __launch_bounds__(256, 2) void forest_fused(
    const bf16* __restrict__ xh, const bf16* __restrict__ xl,
    const bf16* __restrict__ wh, const bf16* __restrict__ wl,
    const float* __restrict__ bias,
    unsigned char* __restrict__ idxb,       // [8192][100] leaf index
    unsigned int* __restrict__ qcount, unsigned int* __restrict__ queue)
{
    __shared__ char lds[65536];   // B hi @0 (32KB), B lo @32768; C overlays @0
    float* C = (float*)lds;       // [128][65] fp32 after k-loop barrier

    const int tid  = threadIdx.x;
    const int wave = tid >> 6;
    const int lane = tid & 63;
    const int m    = lane & 15;
    const int q    = lane >> 4;
    const int ng   = blockIdx.x;             // tree-group 0..24 (4 trees)
    const int mg   = blockIdx.y;             // sample-tile 0..63 (128 samples)
    const int sbase = mg * 128;
    const int rowbase = ng * 64;             // W-split flat row base (of 1600)

    // bias regs: biasv[ni] = bias[tree(ni)][node m]  (L2-resident, tiny)
    float biasv[4];
#pragma unroll
    for (int ni = 0; ni < 4; ++ni)
        biasv[ni] = bias[(size_t)(ng * 4 + ni) * NNODES + m];

    // ---- stage B hi+lo into LDS, XOR-swizzled chunks (16B chunk c of row n
    //      stored at position c ^ (n&7)) so B-frag ds_read_b128 is 8-cycle.
#pragma unroll
    for (int j = 0; j < 8; ++j) {
        int ch = j * 256 + tid;              // 0..2047
        int n  = ch >> 5;
        int cp = ch & 31;
        int c  = cp ^ (n & 7);
        uint4 vh = *(const uint4*)(wh + ((size_t)(rowbase + n) * ND) + c * 8);
        uint4 vl = *(const uint4*)(wl + ((size_t)(rowbase + n) * ND) + c * 8);
        *(uint4*)(lds + n * 512 + cp * 16)         = vh;
        *(uint4*)(lds + 32768 + n * 512 + cp * 16) = vl;
    }
    __syncthreads();

    f32x4 acc[2][4];
#pragma unroll
    for (int mi = 0; mi < 2; ++mi)
#pragma unroll
        for (int ni = 0; ni < 4; ++ni)
            acc[mi][ni] = (f32x4){0.f, 0.f, 0.f, 0.f};

    const int gbase = mg * 8 + wave * 2;     // sample-group index (of 512)

#pragma unroll
    for (int kc = 0; kc < 2; ++kc) {
        // A-frags for this K-chunk: short-lived (64 VGPRs hi+lo), coalesced 1KB loads
        bf16x8 ah[2][4], al[2][4];
#pragma unroll
        for (int mi = 0; mi < 2; ++mi)
#pragma unroll
            for (int kk = 0; kk < 4; ++kk) {
                size_t off = (size_t)(gbase + mi) * 4096
                           + (size_t)(kc * 16 + kk * 4) * 128 + lane * 8;
                ah[mi][kk] = *(const bf16x8*)(xh + off);
                al[mi][kk] = *(const bf16x8*)(xl + off);
            }
#pragma unroll
        for (int kk = 0; kk < 4; ++kk) {
            const int k = kc * 4 + kk;       // global k-step 0..7
#pragma unroll
            for (int ni = 0; ni < 4; ++ni) {
                const int n    = ni * 16 + m;
                const int cidx = (4 * k + q) ^ (m & 7);
                bf16x8 bh = *(const bf16x8*)(lds + n * 512 + cidx * 16);
                bf16x8 bl = *(const bf16x8*)(lds + 32768 + n * 512 + cidx * 16);
#pragma unroll
                for (int mi = 0; mi < 2; ++mi) {
                    acc[mi][ni] = __builtin_amdgcn_mfma_f32_16x16x32_bf16(al[mi][kk], bh, acc[mi][ni], 0, 0, 0);
                    acc[mi][ni] = __builtin_amdgcn_mfma_f32_16x16x32_bf16(ah[mi][kk], bl, acc[mi][ni], 0, 0, 0);
                    acc[mi][ni] = __builtin_amdgcn_mfma_f32_16x16x32_bf16(ah[mi][kk], bh, acc[mi][ni], 0, 0, 0);
                }
            }
        }
    }
    __syncthreads();   // B dead; LDS becomes C

    // C/D layout: col = lane&15 (node), row = q*4 + reg (sample). Add bias here.
#pragma unroll
    for (int mi = 0; mi < 2; ++mi)
#pragma unroll
        for (int ni = 0; ni < 4; ++ni)
#pragma unroll
            for (int r = 0; r < 4; ++r)
                C[(wave * 32 + mi * 16 + q * 4 + r) * 65 + ni * 16 + m] =
                    acc[mi][ni][r] + biasv[ni];
    __syncthreads();

    // ---- traversal: 512 (s,t) pairs, 2 per thread (same s, two trees)
    {
        const int s  = tid >> 1;
        const int t0 = (tid & 1) * 2;
        const int sg = sbase + s;
#pragma unroll
        for (int u = 0; u < 2; ++u) {
            const int tl = t0 + u;
            const float* row = &C[s * 65 + tl * 16];
            int node = 0;
            float mn = 1e30f;
#pragma unroll
            for (int lvl = 0; lvl < 5; ++lvl) {
                float z = row[node];
                mn = fminf(mn, fabsf(z));
                node = 2 * node + (z <= 0.0f ? 1 : 0);
            }
            const int tg = ng * 4 + tl;
            idxb[(size_t)sg * NTREES + tg] = (unsigned char)node;
            if (mn < TAU) {
                unsigned int pos = atomicAdd(qcount, 1u);
                if (pos < QCAP) queue[pos] = ((unsigned)tg << 13) | (unsigned)sg;
            }
        }
    }
}

// ---- K4: exact fp64 re-traversal of queued near-tie samples ------------------
__global__ void fixup_kernel(const float* __restrict__ x, const float* __restrict__ wf,
                             const float* __restrict__ bias,
                             const unsigned int* __restrict__ qcount,
                             const unsigned int* __restrict__ queue,
                             unsigned char* __restrict__ idxb) {
    const int wid  = (blockIdx.x * 256 + threadIdx.x) >> 6;   // 0..255
    const int lane = threadIdx.x & 63;
    unsigned int n = *qcount;
    if (n > QCAP) n = QCAP;
    for (unsigned int it = wid; it < n; it += 256) {
        unsigned int e = queue[it];
        int t = e >> 13, s = e & 8191;
        const float* xr = x + (size_t)s * ND;
        float4 xv = *(const float4*)(xr + lane * 4);
        int node = 0;
        for (int lvl = 0; lvl < 5; ++lvl) {
            const float* wr = wf + ((size_t)t * NNODES + node) * ND;
            float4 wv = *(const float4*)(wr + lane * 4);
            double zz = (double)xv.x * wv.x + (double)xv.y * wv.y
                      + (double)xv.z * wv.z + (double)xv.w * wv.w;
#pragma unroll
            for (int o = 32; o > 0; o >>= 1) zz += __shfl_xor(zz, o);
            zz += (double)bias[t * NNODES + node];
            node = 2 * node + (zz <= 0.0 ? 1 : 0);
        }
        if (lane == 0) idxb[(size_t)s * NTREES + t] = (unsigned char)node;
    }
}

// ---- K5: leaf gather + forest mean (wave per sample, lane = class) ----------
__global__ void leaf_gather(const unsigned char* __restrict__ idxb,
                            const float* __restrict__ leaves,
                            float* __restrict__ out) {
    const int wave = threadIdx.x >> 6;
    const int lane = threadIdx.x & 63;
    const int s = blockIdx.x * 4 + wave;
    unsigned int rw = 0;
    if (lane < 25) rw = *(const unsigned int*)(idxb + (size_t)s * NTREES + lane * 4);
    float acc = 0.f;
#pragma unroll 10
    for (int t = 0; t < NTREES; ++t) {
        unsigned int wrd = __shfl(rw, t >> 2);
        int li = (wrd >> ((t & 3) * 8)) & 255;
        acc += leaves[((size_t)t * NLEAF + li) * NCLS + lane];
    }
    out[(size_t)s * NCLS + lane] = acc * 0.01f;
}

// ---------------------------------------------------------------------------
extern "C" void kernel_launch(void* const* d_in, const int* in_sizes, int n_in,
                              void* d_out, int out_size, void* d_ws, size_t ws_size,
                              hipStream_t stream) {
    const float* x  = (const float*)d_in[0];   // [8192,256]
    const float* nw = (const float*)d_in[1];   // [100,31,256]
    const float* nb = (const float*)d_in[2];   // [100,31]
    const float* lv = (const float*)d_in[3];   // [100,32,64]
    float* out = (float*)d_out;

    char* ws = (char*)d_ws;
    bf16* xh = (bf16*)(ws + 0);                       // 4,194,304
    bf16* xl = (bf16*)(ws + 4194304);                 // 4,194,304
    bf16* wh = (bf16*)(ws + 8388608);                 //   819,200
    bf16* wl = (bf16*)(ws + 9207808);                 //   819,200
    unsigned char* idxb = (unsigned char*)(ws + 10027008);  // 819,200
    unsigned int* qcount = (unsigned int*)(ws + 10846208);  // 16
    unsigned int* queue  = (unsigned int*)(ws + 10846224);  // 32,768
    if (ws_size < (size_t)10878992) return;

    hipMemsetAsync(qcount, 0, 4, stream);
    split_x_swz<<<NB * ND / (256 * 8), 256, 0, stream>>>(x, xh, xl);
    split_w_kernel<<<NTREES * NUSED * ND / 256, 256, 0, stream>>>(nw, wh, wl);
    forest_fused<<<dim3(NTREES / 4, NB / 128), 256, 0, stream>>>(
        xh, xl, wh, wl, nb, idxb, qcount, queue);
    fixup_kernel<<<64, 256, 0, stream>>>(x, nw, nb, qcount, queue, idxb);
    leaf_gather<<<NB / 4, 256, 0, stream>>>(idxb, lv, out);
}

// Round 3
// 118.505 us; speedup vs baseline: 1.9008x; 1.0209x over previous
//
#include <hip/hip_runtime.h>

// ---------------------------------------------------------------------------
// RandomForest: 100 trees, depth 5, D=256, B=8192, C=64.
//  * decision = sign(w.x + b); only node rows 0..15 route.
//  * Fused GEMM Z[8192 x 1600] = X.W^T (+bias), split-bf16 3-MFMA, traversal
//    in epilogue; near-ties (|z|<TAU) queued for exact fp64 re-traversal.
//  * R3: M=256/block, B staged per-K-half from fp32 w (split_w fused),
//    3 blocks/CU (49KB LDS, <=170 VGPR), 4 launches total.
// ---------------------------------------------------------------------------

typedef __bf16 bf16;
typedef __attribute__((ext_vector_type(8))) __bf16 bf16x8;
typedef __attribute__((ext_vector_type(4))) float f32x4;

#define NTREES 100
#define NB     8192
#define ND     256
#define NNODES 31
#define NLEAF  32
#define NCLS   64
#define TAU    2.0e-3f
#define QCAP   8192

// ---- K1: split fp32 X -> bf16 hi/lo, A-operand-swizzled; zero qcount -------
// elem index = g*4096 + dq*128 + m*8 + e  ==  X[g*16+m][dq*8+e]
__global__ void split_x_swz(const float* __restrict__ x,
                            bf16* __restrict__ xh, bf16* __restrict__ xl,
                            unsigned int* __restrict__ qcount) {
    if (blockIdx.x == 0 && threadIdx.x == 0) *qcount = 0;
    int i = blockIdx.x * 256 + threadIdx.x;       // 0 .. 262143
    int m  = i & 15;
    int dq = (i >> 4) & 31;
    int g  = i >> 9;
    const float* src = x + (size_t)(g * 16 + m) * ND + dq * 8;
    bf16x8 h8, l8;
#pragma unroll
    for (int e = 0; e < 8; ++e) {
        float f = src[e];
        bf16 h = (bf16)f;
        h8[e] = h;
        l8[e] = (bf16)(f - (float)h);
    }
    *(bf16x8*)(xh + (size_t)i * 8) = h8;
    *(bf16x8*)(xl + (size_t)i * 8) = l8;
}

// ---- K2: fused GEMM + traversal ---------------------------------------------
// block: 256 samples x 4 trees. 4 waves, each M=64 (mi=0..3), N=64 (ni=0..3).
__global__ __launch_bounds__(256, 3) void forest_fused(
    const bf16* __restrict__ xh, const bf16* __restrict__ xl,
    const float* __restrict__ wf,      // fp32 node_w [100][31][256]
    const float* __restrict__ bias,    // fp32 node_b [100][31]
    unsigned char* __restrict__ idxb,  // [8192][100] leaf index
    unsigned int* __restrict__ qcount, unsigned int* __restrict__ queue)
{
    __shared__ char lds[50176];
    bf16*  Wh  = (bf16*)lds;               // [64 rows][128 k] swizzled, 16KB
    bf16*  Wl  = (bf16*)(lds + 16384);     // 16KB
    float* scr = (float*)(lds + 32768);    // [4 waves][64][17]  17.4KB

    const int tid  = threadIdx.x;
    const int wave = tid >> 6;
    const int lane = tid & 63;
    const int m    = lane & 15;
    const int q    = lane >> 4;
    const int tg   = blockIdx.x;           // tree-group 0..24
    const int mg   = blockIdx.y;           // sample-tile 0..31 (256 samples)
    const int gbase = mg * 16 + wave * 4;  // sample-group base (16 samples ea)

    float biasv[4];
#pragma unroll
    for (int ni = 0; ni < 4; ++ni)
        biasv[ni] = bias[(size_t)(tg * 4 + ni) * NNODES + m];

    f32x4 acc[4][4];
#pragma unroll
    for (int mi = 0; mi < 4; ++mi)
#pragma unroll
        for (int ni = 0; ni < 4; ++ni)
            acc[mi][ni] = (f32x4){0.f, 0.f, 0.f, 0.f};

    // staging identity for this thread: row n, chunks c = (lane>>4) + 4*it
    const int srow = wave * 16 + (lane & 15);
    const float* wrow = wf + ((size_t)(tg * 4 + (srow >> 4)) * NNODES + (srow & 15)) * ND;

#pragma unroll
    for (int kc = 0; kc < 2; ++kc) {
        __syncthreads();   // all waves done reading previous B half
        // ---- stage B half (64 rows x 128 k, hi+lo) from fp32 w, XOR-swizzled
#pragma unroll
        for (int it = 0; it < 4; ++it) {
            int c = (lane >> 4) + it * 4;            // k-octet 0..15
            const float* src = wrow + kc * 128 + c * 8;
            float4 f0 = *(const float4*)(src);
            float4 f1 = *(const float4*)(src + 4);
            float fv[8] = {f0.x, f0.y, f0.z, f0.w, f1.x, f1.y, f1.z, f1.w};
            bf16x8 h8, l8;
#pragma unroll
            for (int e = 0; e < 8; ++e) {
                bf16 h = (bf16)fv[e];
                h8[e] = h;
                l8[e] = (bf16)(fv[e] - (float)h);
            }
            int swz = c ^ (srow & 7);
            *(bf16x8*)(Wh + srow * 128 + swz * 8) = h8;
            *(bf16x8*)(Wl + srow * 128 + swz * 8) = l8;
        }
        __syncthreads();

        // ---- K-loop: 4 kk-steps, A prefetched one kk ahead
        bf16x8 cah[4], cal[4], nah[4], nal[4];
#pragma unroll
        for (int mi = 0; mi < 4; ++mi) {
            size_t off = (size_t)(gbase + mi) * 4096 + (size_t)(kc * 16) * 128 + lane * 8;
            cah[mi] = *(const bf16x8*)(xh + off);
            cal[mi] = *(const bf16x8*)(xl + off);
        }
#pragma unroll
        for (int kk = 0; kk < 4; ++kk) {
            if (kk < 3) {
#pragma unroll
                for (int mi = 0; mi < 4; ++mi) {
                    size_t off = (size_t)(gbase + mi) * 4096
                               + (size_t)(kc * 16 + (kk + 1) * 4) * 128 + lane * 8;
                    nah[mi] = *(const bf16x8*)(xh + off);
                    nal[mi] = *(const bf16x8*)(xl + off);
                }
            }
#pragma unroll
            for (int ni = 0; ni < 4; ++ni) {
                const int n    = ni * 16 + m;
                const int cidx = (4 * kk + q) ^ (m & 7);
                bf16x8 bh = *(const bf16x8*)(Wh + n * 128 + cidx * 8);
                bf16x8 bl = *(const bf16x8*)(Wl + n * 128 + cidx * 8);
#pragma unroll
                for (int mi = 0; mi < 4; ++mi) {
                    acc[mi][ni] = __builtin_amdgcn_mfma_f32_16x16x32_bf16(cal[mi], bh, acc[mi][ni], 0, 0, 0);
                    acc[mi][ni] = __builtin_amdgcn_mfma_f32_16x16x32_bf16(cah[mi], bl, acc[mi][ni], 0, 0, 0);
                    acc[mi][ni] = __builtin_amdgcn_mfma_f32_16x16x32_bf16(cah[mi], bh, acc[mi][ni], 0, 0, 0);
                }
            }
#pragma unroll
            for (int mi = 0; mi < 4; ++mi) { cah[mi] = nah[mi]; cal[mi] = nal[mi]; }
        }
    }

    // ---- epilogue: per-tree LDS round-trip + traversal --------------------
    float* ws_ = scr + wave * (64 * 17);
    const int sg = mg * 256 + wave * 64 + lane;    // this lane's global sample
    unsigned int pk = 0;
#pragma unroll
    for (int ni = 0; ni < 4; ++ni) {
        // write: D row = q*4+r (sample within 16), col = m (node)
#pragma unroll
        for (int mi = 0; mi < 4; ++mi)
#pragma unroll
            for (int r = 0; r < 4; ++r)
                ws_[(mi * 16 + q * 4 + r) * 17 + m] = acc[mi][ni][r] + biasv[ni];
        __syncthreads();
        // walk: lane handles its sample row
        int node = 0;
        float mn = 1e30f;
#pragma unroll
        for (int lvl = 0; lvl < 5; ++lvl) {
            float z = ws_[lane * 17 + node];
            mn = fminf(mn, fabsf(z));
            node = 2 * node + (z <= 0.0f ? 1 : 0);
        }
        pk |= (unsigned)node << (8 * ni);
        if (mn < TAU) {
            unsigned int pos = atomicAdd(qcount, 1u);
            if (pos < QCAP)
                queue[pos] = ((unsigned)(tg * 4 + ni) << 13) | (unsigned)sg;
        }
        __syncthreads();   // protect next ni's writes from this walk's reads
    }
    *(unsigned int*)(idxb + (size_t)sg * NTREES + tg * 4) = pk;
}

// ---- K3: exact fp64 re-traversal of queued near-ties ------------------------
__global__ void fixup_kernel(const float* __restrict__ x, const float* __restrict__ wf,
                             const float* __restrict__ bias,
                             const unsigned int* __restrict__ qcount,
                             const unsigned int* __restrict__ queue,
                             unsigned char* __restrict__ idxb) {
    const int wid  = (blockIdx.x * 256 + threadIdx.x) >> 6;   // 0..255
    const int lane = threadIdx.x & 63;
    unsigned int n = *qcount;
    if (n > QCAP) n = QCAP;
    for (unsigned int it = wid; it < n; it += 256) {
        unsigned int e = queue[it];
        int t = e >> 13, s = e & 8191;
        const float* xr = x + (size_t)s * ND;
        float4 xv = *(const float4*)(xr + lane * 4);
        int node = 0;
        for (int lvl = 0; lvl < 5; ++lvl) {
            const float* wr = wf + ((size_t)t * NNODES + node) * ND;
            float4 wv = *(const float4*)(wr + lane * 4);
            double zz = (double)xv.x * wv.x + (double)xv.y * wv.y
                      + (double)xv.z * wv.z + (double)xv.w * wv.w;
#pragma unroll
            for (int o = 32; o > 0; o >>= 1) zz += __shfl_xor(zz, o);
            zz += (double)bias[t * NNODES + node];
            node = 2 * node + (zz <= 0.0 ? 1 : 0);
        }
        if (lane == 0) idxb[(size_t)s * NTREES + t] = (unsigned char)node;
    }
}

// ---- K4: leaf gather + forest mean (wave per sample, lane = class) ----------
__global__ void leaf_gather(const unsigned char* __restrict__ idxb,
                            const float* __restrict__ leaves,
                            float* __restrict__ out) {
    const int wave = threadIdx.x >> 6;
    const int lane = threadIdx.x & 63;
    const int s = blockIdx.x * 4 + wave;
    unsigned int rw = 0;
    if (lane < 25) rw = *(const unsigned int*)(idxb + (size_t)s * NTREES + lane * 4);
    float acc = 0.f;
#pragma unroll 10
    for (int t = 0; t < NTREES; ++t) {
        unsigned int wrd = __shfl(rw, t >> 2);
        int li = (wrd >> ((t & 3) * 8)) & 255;
        acc += leaves[((size_t)t * NLEAF + li) * NCLS + lane];
    }
    out[(size_t)s * NCLS + lane] = acc * 0.01f;
}

// ---------------------------------------------------------------------------
extern "C" void kernel_launch(void* const* d_in, const int* in_sizes, int n_in,
                              void* d_out, int out_size, void* d_ws, size_t ws_size,
                              hipStream_t stream) {
    const float* x  = (const float*)d_in[0];   // [8192,256]
    const float* nw = (const float*)d_in[1];   // [100,31,256]
    const float* nb = (const float*)d_in[2];   // [100,31]
    const float* lv = (const float*)d_in[3];   // [100,32,64]
    float* out = (float*)d_out;

    char* ws = (char*)d_ws;
    bf16* xh = (bf16*)(ws + 0);                             // 4,194,304
    bf16* xl = (bf16*)(ws + 4194304);                       // 4,194,304
    unsigned char* idxb  = (unsigned char*)(ws + 8388608);  //   819,200
    unsigned int* qcount = (unsigned int*)(ws + 9207808);   //        16
    unsigned int* queue  = (unsigned int*)(ws + 9207824);   //    32,768
    if (ws_size < (size_t)9240592) return;

    split_x_swz<<<NB * ND / (256 * 8), 256, 0, stream>>>(x, xh, xl, qcount);
    forest_fused<<<dim3(NTREES / 4, NB / 256), 256, 0, stream>>>(
        xh, xl, nw, nb, idxb, qcount, queue);
    fixup_kernel<<<64, 256, 0, stream>>>(x, nw, nb, qcount, queue, idxb);
    leaf_gather<<<NB / 4, 256, 0, stream>>>(idxb, lv, out);
}